// Round 1
// baseline (367.425 us; speedup 1.0000x reference)
//
#include <hip/hip_runtime.h>
#include <math.h>

#define M_DIM 1024
#define K_DIM 32
#define N_DIM 2048
#define PGD_ITERS 1500

// ws layout (float offsets)
#define G_OFF   0        // 32*32 = 1024 floats
#define LAM_OFF 1024     // 1 float
#define T_OFF   2048     // 32*2048 = 65536 floats

// ---------------------------------------------------------------------------
// G = theta_c^T theta_c, theta_c = max(theta, 0).  One block per entry (i,j).
__global__ void kGram(const float* __restrict__ theta, float* __restrict__ G) {
    int e = blockIdx.x;           // 0..1023
    int i = e >> 5, j = e & 31;
    int tid = threadIdx.x;        // 256 threads
    float p = 0.f;
    for (int m = tid; m < M_DIM; m += 256) {
        float a = fmaxf(theta[m * K_DIM + i], 0.f);
        float b = fmaxf(theta[m * K_DIM + j], 0.f);
        p = fmaf(a, b, p);
    }
    __shared__ float red[256];
    red[tid] = p;
    __syncthreads();
    for (int s = 128; s > 0; s >>= 1) {
        if (tid < s) red[tid] += red[tid + s];
        __syncthreads();
    }
    if (tid == 0) G[e] = red[0];
}

// ---------------------------------------------------------------------------
// T = theta_c^T X  (32 x 2048).  grid = (8 col-blocks, 8 m-splits), block 256.
// Each block stages a 128x32 clamped theta tile in LDS, accumulates 32
// partial dots per thread (one column each), atomicAdd-combines into T.
__global__ void kTmat(const float* __restrict__ X, const float* __restrict__ theta,
                      float* __restrict__ T) {
    __shared__ float th[128][32];
    int tid = threadIdx.x;
    int m0 = blockIdx.y * 128;
#pragma unroll
    for (int q = 0; q < 16; ++q) {
        int e = q * 256 + tid;            // 0..4095, coalesced
        th[e >> 5][e & 31] = fmaxf(theta[(m0 + (e >> 5)) * K_DIM + (e & 31)], 0.f);
    }
    __syncthreads();
    int col = blockIdx.x * 256 + tid;
    float acc[32];
#pragma unroll
    for (int i = 0; i < 32; ++i) acc[i] = 0.f;
    for (int mm = 0; mm < 128; ++mm) {
        float x = X[(m0 + mm) * N_DIM + col];
#pragma unroll
        for (int i = 0; i < 32; ++i) acc[i] = fmaf(th[mm][i], x, acc[i]);
    }
#pragma unroll
    for (int i = 0; i < 32; ++i) atomicAdd(&T[i * N_DIM + col], acc[i]);
}

// ---------------------------------------------------------------------------
// Power iteration for lambda_max(G).  Single block, 256 threads (32 active).
// G is an all-positive Gram matrix -> spectral gap is enormous; 64 iterations
// converge far past f32 precision.  PGD only needs L within 2x of lambda_max.
__global__ void kPow(const float* __restrict__ G, float* __restrict__ lam) {
    __shared__ float Gs[32][33];
    __shared__ float v[32];
    __shared__ float red[32];
    __shared__ float lsh;
    int tid = threadIdx.x;
#pragma unroll
    for (int q = 0; q < 4; ++q) {
        int e = q * 256 + tid;
        Gs[e >> 5][e & 31] = G[e];
    }
    if (tid < 32) v[tid] = 1.f;
    __syncthreads();
    float w = 0.f;
    for (int it = 0; it < 64; ++it) {
        if (tid < 32) {
            w = 0.f;
#pragma unroll
            for (int j = 0; j < 32; ++j) w = fmaf(Gs[tid][j], v[j], w);
            red[tid] = w * w;
        }
        __syncthreads();
        if (tid == 0) {
            float s = 0.f;
            for (int j = 0; j < 32; ++j) s += red[j];
            lsh = sqrtf(s);
        }
        __syncthreads();
        if (tid < 32) v[tid] = w / lsh;
        __syncthreads();
    }
    if (tid == 0) lam[0] = lsh;
}

// ---------------------------------------------------------------------------
// Main PGD: b <- max(A b + t, 0), A = I - G/L (per-lane row in registers),
// t = T/L.  Lane = (row i = tid&31, column = tid>>5 within block).  Each wave
// owns 2 columns (2 disjoint LDS rows) -> no __syncthreads in the loop; LDS
// in-order per-wave DS processing gives cross-lane visibility.
__global__ void __launch_bounds__(256) kPGD(const float* __restrict__ G,
                                            const float* __restrict__ lam,
                                            const float* __restrict__ T,
                                            float* __restrict__ out) {
    __shared__ float Gsh[32][33];
    __shared__ float bsh[8][36];   // 36-pad: rows start on distinct banks
    int tid = threadIdx.x;
#pragma unroll
    for (int q = 0; q < 4; ++q) {
        int e = q * 256 + tid;
        Gsh[e >> 5][e & 31] = G[e];
    }
    int i = tid & 31;
    int myrow = tid >> 5;                    // 0..7
    int col = blockIdx.x * 8 + myrow;
    float invL = 1.0f / (lam[0] + 1e-6f);
    bsh[myrow][i] = 0.f;
    __syncthreads();

    float a[32];
#pragma unroll
    for (int j = 0; j < 32; ++j)
        a[j] = ((j == i) ? 1.0f : 0.0f) - Gsh[i][j] * invL;
    float t = T[i * N_DIM + col] * invL;

    const float4* brow = reinterpret_cast<const float4*>(&bsh[myrow][0]);
    float bn = 0.f;
    for (int it = 0; it < PGD_ITERS; ++it) {
        float acc0 = t, acc1 = 0.f, acc2 = 0.f, acc3 = 0.f;
#pragma unroll
        for (int k = 0; k < 8; ++k) {
            float4 vv = brow[k];
            acc0 = fmaf(a[4 * k + 0], vv.x, acc0);
            acc1 = fmaf(a[4 * k + 1], vv.y, acc1);
            acc2 = fmaf(a[4 * k + 2], vv.z, acc2);
            acc3 = fmaf(a[4 * k + 3], vv.w, acc3);
        }
        bn = fmaxf((acc0 + acc1) + (acc2 + acc3), 0.f);
        __builtin_amdgcn_wave_barrier();     // pin read-before-write order
        bsh[myrow][i] = bn;
        __builtin_amdgcn_wave_barrier();
    }
    out[i * N_DIM + col] = bn;
}

// ---------------------------------------------------------------------------
extern "C" void kernel_launch(void* const* d_in, const int* in_sizes, int n_in,
                              void* d_out, int out_size, void* d_ws, size_t ws_size,
                              hipStream_t stream) {
    const float* X     = (const float*)d_in[0];   // (1024, 2048) f32
    const float* theta = (const float*)d_in[1];   // (1024, 32) f32
    float* ws  = (float*)d_ws;
    float* G   = ws + G_OFF;
    float* lam = ws + LAM_OFF;
    float* T   = ws + T_OFF;

    hipMemsetAsync(T, 0, (size_t)K_DIM * N_DIM * sizeof(float), stream);
    kGram<<<1024, 256, 0, stream>>>(theta, G);
    kTmat<<<dim3(8, 8), 256, 0, stream>>>(X, theta, T);
    kPow<<<1, 256, 0, stream>>>(G, lam);
    kPGD<<<256, 256, 0, stream>>>(G, lam, T, (float*)d_out);
}